// Round 10
// baseline (226.625 us; speedup 1.0000x reference)
//
#include <hip/hip_runtime.h>
#include <hip/hip_bf16.h>

#define NN 4096
#define FF 512
#define NH 8
#define DH 64

typedef __attribute__((ext_vector_type(8))) short bf16x8;
typedef __attribute__((ext_vector_type(4))) float f32x4;

// ws layout in ushort elements:
//  X_BF  [4096][512]                    @ 0
//  W_BF  [3][512][512]                  @ 2097152   (Wq pre-scaled by 1/sqrt(512))
//  QF    [8][256 blk][2 half][64 ln][8] @ 2883584   (MFMA A-fragment order)
//  KF    [8][256 blk][2 half][64 ln][8] @ 4980736   (MFMA B-fragment order)
//  VF    [8][64 kb][4 dt][2 hf][64][8]  @ 7077888   (MFMA B-fragment order, d-major)
//  PACC  bf16 [8 ks][8 h][4096][64]     @ 9175040   (16777216 ushorts)
//  PDEN  f32  [8 ks][8 h][4096]         @ 25952256  (524288 ushorts)
#define X_OFF  0
#define W_OFF  2097152
#define QF_OFF 2883584
#define KF_OFF 4980736
#define VF_OFF 7077888
#define PACC_OFF 9175040
#define PDEN_USHORT_OFF 25952256

__device__ __forceinline__ ushort f2bf(float f) {
    __hip_bfloat16 h = __float2bfloat16(f);
    return __builtin_bit_cast(ushort, h);
}
__device__ __forceinline__ float bf2f(ushort u) {
    unsigned int v = ((unsigned int)u) << 16;
    return __builtin_bit_cast(float, v);
}

// ---------------- kernel 0: f32 -> bf16 convert (x, Wq*scale, Wk, Wv) ----------------
__global__ __launch_bounds__(256) void cvt_kernel(const float* __restrict__ x,
                                                  const float* __restrict__ wq,
                                                  const float* __restrict__ wk,
                                                  const float* __restrict__ wv,
                                                  ushort* __restrict__ ws) {
    int i = blockIdx.x * 256 + threadIdx.x;
    int base = i * 4;
    const float* src;
    int off;
    float sc = 1.f;
    if (base < 2097152) { src = x; off = base; }
    else {
        int t = base - 2097152;
        int m = t >> 18;
        src = (m == 0) ? wq : ((m == 1) ? wk : wv);
        if (m == 0) sc = 0.044194173824159216f;   // 1/sqrt(512) folded into Wq
        off = t & 262143;
    }
    float4 v = *reinterpret_cast<const float4*>(src + off);
    ushort4 o;
    o.x = f2bf(v.x * sc); o.y = f2bf(v.y * sc); o.z = f2bf(v.z * sc); o.w = f2bf(v.w * sc);
    *reinterpret_cast<ushort4*>(ws + base) = o;
}

// ---------------- kernel 1: QKV projection, outputs in MFMA-fragment order ----------------
__global__ __launch_bounds__(256) void qkv_kernel(ushort* __restrict__ ws) {
    int bx = blockIdx.x;
    int mat = bx >> 3;          // 0=Q,1=K,2=V
    int fb  = bx & 7;           // head
    int mb  = blockIdx.y;
    int wave = threadIdx.x >> 6, lane = threadIdx.x & 63;
    int la = lane & 15, lk = lane >> 4;

    int m_base = mb * 64 + wave * 16;
    int f_base = fb * 64;

    const ushort* xb = ws + X_OFF;
    const ushort* wb = ws + W_OFF + mat * 262144;

    f32x4 acc[4];
#pragma unroll
    for (int t = 0; t < 4; ++t) acc[t] = (f32x4){0.f, 0.f, 0.f, 0.f};

#pragma unroll 4
    for (int k0 = 0; k0 < 512; k0 += 32) {
        bf16x8 a = *reinterpret_cast<const bf16x8*>(xb + (size_t)(m_base + la) * 512 + k0 + lk * 8);
#pragma unroll
        for (int ft = 0; ft < 4; ++ft) {
            bf16x8 b = *reinterpret_cast<const bf16x8*>(wb + (size_t)(f_base + ft * 16 + la) * 512 + k0 + lk * 8);
            acc[ft] = __builtin_amdgcn_mfma_f32_16x16x32_bf16(a, b, acc[ft], 0, 0, 0);
        }
    }

#pragma unroll
    for (int ft = 0; ft < 4; ++ft) {
#pragma unroll
        for (int r = 0; r < 4; ++r) {
            int n = m_base + lk * 4 + r;
            int d = ft * 16 + la;          // head-local feature
            ushort v = f2bf(acc[ft][r]);
            if (mat < 2) {
                ushort* base = ws + (mat == 0 ? QF_OFF : KF_OFF) + (size_t)fb * 262144;
                int blk = n >> 4, rr = n & 15;
                int half = d >> 5, lkk = (d >> 3) & 3, e = d & 7;
                base[(((size_t)blk * 2 + half) * 64 + lkk * 16 + rr) * 8 + e] = v;
            } else {
                ushort* base = ws + VF_OFF + (size_t)fb * 262144;
                int kb64 = n >> 6, kc = n & 63;
                int hf = kc >> 5, lkv = (kc >> 3) & 3, ev = kc & 7;
                int dt = d >> 4, lav = d & 15;
                base[((((size_t)kb64 * 4 + dt) * 2 + hf) * 64 + lkv * 16 + lav) * 8 + ev] = v;
            }
        }
    }
}

// ---------------- kernel 2: masked attention, low-VGPR counted-vmcnt pipeline ----------------
// grid 4096: h = bid&7 (XCD-pinned), qb = (bid>>3)&63, ks = bid>>9 (0..7).
// 4 waves x 16 q-rows; 8 bodies of 64 keys each (512 keys per block).
// FIFO invariant at every body top: [stage4(this body), adj16(this body)] ->
// s_waitcnt vmcnt(16) drains exactly the stage; adj loads stay in flight into
// the body and are consumed per-kt (compiler inserts the per-reg waits).
// Per-kt fused mask+exp keeps live VGPR ~70 -> fits the (256,3) cap of 85, NO SPILLS.

#define STAGE(BUF, KB)                                                                     \
    {                                                                                      \
        const ushort* sbase_ = (wave < 2) ? Kh : Vh;                                       \
        ushort(*dbuf_)[512] = (wave < 2) ? kbuf[BUF] : vbuf[BUF];                          \
        int t0_ = (wave & 1) * 4;                                                          \
        _Pragma("unroll")                                                                  \
        for (int t_ = 0; t_ < 4; ++t_) {                                                   \
            int tile_ = t0_ + t_;                                                          \
            const ushort* src_ = sbase_ +                                                  \
                (((size_t)(KB) * 4 + (tile_ >> 1)) * 2 + (tile_ & 1)) * 512 + lane * 8;    \
            __builtin_amdgcn_global_load_lds(                                              \
                (const __attribute__((address_space(1))) unsigned int*)src_,               \
                (__attribute__((address_space(3))) unsigned int*)&dbuf_[tile_][0],         \
                16, 0, 0);                                                                 \
        }                                                                                  \
    }

__global__ __launch_bounds__(256, 3) void attn_kernel(const int* __restrict__ adj,
                                                      const ushort* __restrict__ ws,
                                                      ushort* __restrict__ pacc,
                                                      float* __restrict__ pden) {
    __shared__ ushort kbuf[2][8][512];   // 16KB
    __shared__ ushort vbuf[2][8][512];   // 16KB
    __shared__ ushort P[4][16][72];      // 9.2KB per-wave P staging

    int bid = blockIdx.x;
    int h = bid & 7, qb = (bid >> 3) & 63, ks = bid >> 9;
    int wave = threadIdx.x >> 6, lane = threadIdx.x & 63;
    int la = lane & 15, lk = lane >> 4;
    int q0w = qb * 64 + wave * 16;

    const ushort* Qh = ws + QF_OFF + (size_t)h * 262144;
    const ushort* Kh = ws + KF_OFF + (size_t)h * 262144;
    const ushort* Vh = ws + VF_OFF + (size_t)h * 262144;
    const int* adjw = adj + (size_t)h * 16777216 + (size_t)q0w * 4096;

    bf16x8 qa0 = *reinterpret_cast<const bf16x8*>(Qh + ((((size_t)(q0w >> 4)) * 2 + 0) * 64 + lane) * 8);
    bf16x8 qa1 = *reinterpret_cast<const bf16x8*>(Qh + ((((size_t)(q0w >> 4)) * 2 + 1) * 64 + lane) * 8);

    f32x4 acc[4];
    float den[4];
#pragma unroll
    for (int r = 0; r < 4; ++r) {
        acc[r] = (f32x4){0.f, 0.f, 0.f, 0.f};
        den[r] = 0.f;
    }

    const f32x4 zero = {0.f, 0.f, 0.f, 0.f};
    int kbase = ks * 8;   // bodies kbase .. kbase+7 (64 keys each)

    // prologue — FIFO order: [stage4, adj16] for body 0
    int adjv[16];
    STAGE(0, kbase)
    __builtin_amdgcn_sched_barrier(0);
#pragma unroll
    for (int kt = 0; kt < 4; ++kt)
#pragma unroll
        for (int r = 0; r < 4; ++r)
            adjv[kt * 4 + r] = __builtin_nontemporal_load(
                adjw + (size_t)(lk * 4 + r) * 4096 + (size_t)kbase * 64 + kt * 16 + la);
    __builtin_amdgcn_sched_barrier(0);

    for (int it = 0; it < 8; ++it) {
        int kb = kbase + it;
        int cur = it & 1;

        // body top: drain exactly this body's stage; adj16 stays in flight
        asm volatile("s_waitcnt vmcnt(16)" ::: "memory");
        __builtin_amdgcn_s_barrier();
        __builtin_amdgcn_sched_barrier(0);

        // QK^T + fused per-kt mask/exp (adjv consumed element-wise; s transient)
#pragma unroll
        for (int kt = 0; kt < 4; ++kt) {
            bf16x8 kf0 = *reinterpret_cast<const bf16x8*>(&kbuf[cur][kt * 2 + 0][lane * 8]);
            bf16x8 kf1 = *reinterpret_cast<const bf16x8*>(&kbuf[cur][kt * 2 + 1][lane * 8]);
            f32x4 s = __builtin_amdgcn_mfma_f32_16x16x32_bf16(qa0, kf0, zero, 0, 0, 0);
            s = __builtin_amdgcn_mfma_f32_16x16x32_bf16(qa1, kf1, s, 0, 0, 0);
#pragma unroll
            for (int r = 0; r < 4; ++r) {
                float sv = adjv[kt * 4 + r] ? s[r] : -1e30f;
                float e = __expf(sv);
                den[r] += e;
                P[wave][lk * 4 + r][kt * 16 + la] = f2bf(e);
            }
        }

        // PV from LDS-staged V (P: same-wave write->read, lgkm auto-ordered)
        bf16x8 pa0 = *reinterpret_cast<const bf16x8*>(&P[wave][la][lk * 8]);
        bf16x8 pa1 = *reinterpret_cast<const bf16x8*>(&P[wave][la][32 + lk * 8]);
#pragma unroll
        for (int dt = 0; dt < 4; ++dt) {
            bf16x8 vb0 = *reinterpret_cast<const bf16x8*>(&vbuf[cur][dt * 2 + 0][lane * 8]);
            bf16x8 vb1 = *reinterpret_cast<const bf16x8*>(&vbuf[cur][dt * 2 + 1][lane * 8]);
            acc[dt] = __builtin_amdgcn_mfma_f32_16x16x32_bf16(pa0, vb0, acc[dt], 0, 0, 0);
            acc[dt] = __builtin_amdgcn_mfma_f32_16x16x32_bf16(pa1, vb1, acc[dt], 0, 0, 0);
        }

        // body end: issue next body's stage then adj (adjv fully consumed above)
        if (it < 7) {
            __builtin_amdgcn_sched_barrier(0);
            STAGE(cur ^ 1, kb + 1)
            __builtin_amdgcn_sched_barrier(0);
#pragma unroll
            for (int kt = 0; kt < 4; ++kt)
#pragma unroll
                for (int r = 0; r < 4; ++r)
                    adjv[kt * 4 + r] = __builtin_nontemporal_load(
                        adjw + (size_t)(lk * 4 + r) * 4096 + (size_t)(kb + 1) * 64 + kt * 16 + la);
            __builtin_amdgcn_sched_barrier(0);
        }
    }

    // reduce den over the 16-lane key dimension
#pragma unroll
    for (int r = 0; r < 4; ++r)
#pragma unroll
        for (int mm = 1; mm < 16; mm <<= 1)
            den[r] += __shfl_xor(den[r], mm, 64);

    // store bf16 partial acc + f32 partial den
    ushort* pa_out = pacc + ((size_t)ks * 8 + h) * 4096 * 64;
#pragma unroll
    for (int dt = 0; dt < 4; ++dt)
#pragma unroll
        for (int r = 0; r < 4; ++r) {
            int q = q0w + lk * 4 + r;
            __builtin_nontemporal_store(f2bf(acc[dt][r]), pa_out + (size_t)q * 64 + dt * 16 + la);
        }
    if (la == 0) {
        float* pd = pden + ((size_t)ks * 8 + h) * 4096;
#pragma unroll
        for (int r = 0; r < 4; ++r)
            pd[q0w + lk * 4 + r] = den[r];
    }
}

// ---------------- kernel 3: combine bf16 partials + epilogue ----------------
__global__ __launch_bounds__(256) void combine_kernel(const float* __restrict__ x,
                                                      const ushort* __restrict__ pacc,
                                                      const float* __restrict__ pden,
                                                      float* __restrict__ out) {
    int idx = blockIdx.x * 256 + threadIdx.x;   // 524288 total
    int n = idx >> 7, fq = idx & 127;
    int h = fq >> 4;
    int d4 = (fq & 15) * 4;

    float4 o = make_float4(0.f, 0.f, 0.f, 0.f);
    float den = 0.f;
#pragma unroll
    for (int ksp = 0; ksp < 8; ++ksp) {
        const ushort* pa = pacc + (((size_t)ksp * 8 + h) * 4096 + n) * 64 + d4;
        ushort4 p = *reinterpret_cast<const ushort4*>(pa);
        o.x += bf2f(p.x); o.y += bf2f(p.y); o.z += bf2f(p.z); o.w += bf2f(p.w);
        den += pden[((size_t)ksp * 8 + h) * 4096 + n];
    }
    float4 xv = *reinterpret_cast<const float4*>(x + (size_t)n * 512 + fq * 4);
    float inv = 1.f / den;
    float4 r;
    r.x = o.x * inv + xv.x;
    r.y = o.y * inv + xv.y;
    r.z = o.z * inv + xv.z;
    r.w = o.w * inv + xv.w;
    r.x = (r.x > 0.f) ? r.x : (__expf(r.x) - 1.f);
    r.y = (r.y > 0.f) ? r.y : (__expf(r.y) - 1.f);
    r.z = (r.z > 0.f) ? r.z : (__expf(r.z) - 1.f);
    r.w = (r.w > 0.f) ? r.w : (__expf(r.w) - 1.f);
    *reinterpret_cast<float4*>(out + (size_t)n * 512 + fq * 4) = r;
}

extern "C" void kernel_launch(void* const* d_in, const int* in_sizes, int n_in,
                              void* d_out, int out_size, void* d_ws, size_t ws_size,
                              hipStream_t stream) {
    const float* x  = (const float*)d_in[0];
    const float* wq = (const float*)d_in[1];
    const float* wk = (const float*)d_in[2];
    const float* wv = (const float*)d_in[3];
    const int*   adj = (const int*)d_in[4];
    float* out = (float*)d_out;
    ushort* ws = (ushort*)d_ws;
    ushort* pacc = ws + PACC_OFF;
    float* pden = (float*)(ws + PDEN_USHORT_OFF);

    cvt_kernel<<<2816, 256, 0, stream>>>(x, wq, wk, wv, ws);
    qkv_kernel<<<dim3(24, 64), 256, 0, stream>>>(ws);
    attn_kernel<<<4096, 256, 0, stream>>>(adj, ws, pacc, pden);
    combine_kernel<<<2048, 256, 0, stream>>>(x, pacc, pden, out);
}

// Round 11
// 208.840 us; speedup vs baseline: 1.0852x; 1.0852x over previous
//
#include <hip/hip_runtime.h>
#include <hip/hip_bf16.h>

#define NN 4096
#define FF 512
#define NH 8
#define DH 64

typedef __attribute__((ext_vector_type(8))) short bf16x8;
typedef __attribute__((ext_vector_type(4))) float f32x4;

// ws layout in ushort elements:
//  X_BF  [4096][512]                    @ 0
//  W_BF  [3][512][512]                  @ 2097152   (Wq pre-scaled by 1/sqrt(512))
//  QF    [8][256 blk][2 half][64 ln][8] @ 2883584   (MFMA A-fragment order)
//  KF    [8][256 blk][2 half][64 ln][8] @ 4980736   (MFMA B-fragment order)
//  VF    [8][64 kb][4 dt][2 hf][64][8]  @ 7077888   (MFMA B-fragment order, d-major)
//  PACC  bf16 [8 ks][8 h][4096][64]     @ 9175040   (16777216 ushorts)
//  PDEN  f32  [8 ks][8 h][4096]         @ 25952256  (524288 ushorts)
#define X_OFF  0
#define W_OFF  2097152
#define QF_OFF 2883584
#define KF_OFF 4980736
#define VF_OFF 7077888
#define PACC_OFF 9175040
#define PDEN_USHORT_OFF 25952256

__device__ __forceinline__ ushort f2bf(float f) {
    __hip_bfloat16 h = __float2bfloat16(f);
    return __builtin_bit_cast(ushort, h);
}
__device__ __forceinline__ float bf2f(ushort u) {
    unsigned int v = ((unsigned int)u) << 16;
    return __builtin_bit_cast(float, v);
}

// ---------------- kernel 0: f32 -> bf16 convert (x, Wq*scale, Wk, Wv) ----------------
__global__ __launch_bounds__(256) void cvt_kernel(const float* __restrict__ x,
                                                  const float* __restrict__ wq,
                                                  const float* __restrict__ wk,
                                                  const float* __restrict__ wv,
                                                  ushort* __restrict__ ws) {
    int i = blockIdx.x * 256 + threadIdx.x;
    int base = i * 4;
    const float* src;
    int off;
    float sc = 1.f;
    if (base < 2097152) { src = x; off = base; }
    else {
        int t = base - 2097152;
        int m = t >> 18;
        src = (m == 0) ? wq : ((m == 1) ? wk : wv);
        if (m == 0) sc = 0.044194173824159216f;   // 1/sqrt(512) folded into Wq
        off = t & 262143;
    }
    float4 v = *reinterpret_cast<const float4*>(src + off);
    ushort4 o;
    o.x = f2bf(v.x * sc); o.y = f2bf(v.y * sc); o.z = f2bf(v.z * sc); o.w = f2bf(v.w * sc);
    *reinterpret_cast<ushort4*>(ws + base) = o;
}

// ---------------- kernel 1: QKV projection, outputs in MFMA-fragment order ----------------
__global__ __launch_bounds__(256) void qkv_kernel(ushort* __restrict__ ws) {
    int bx = blockIdx.x;
    int mat = bx >> 3;          // 0=Q,1=K,2=V
    int fb  = bx & 7;           // head
    int mb  = blockIdx.y;
    int wave = threadIdx.x >> 6, lane = threadIdx.x & 63;
    int la = lane & 15, lk = lane >> 4;

    int m_base = mb * 64 + wave * 16;
    int f_base = fb * 64;

    const ushort* xb = ws + X_OFF;
    const ushort* wb = ws + W_OFF + mat * 262144;

    f32x4 acc[4];
#pragma unroll
    for (int t = 0; t < 4; ++t) acc[t] = (f32x4){0.f, 0.f, 0.f, 0.f};

#pragma unroll 4
    for (int k0 = 0; k0 < 512; k0 += 32) {
        bf16x8 a = *reinterpret_cast<const bf16x8*>(xb + (size_t)(m_base + la) * 512 + k0 + lk * 8);
#pragma unroll
        for (int ft = 0; ft < 4; ++ft) {
            bf16x8 b = *reinterpret_cast<const bf16x8*>(wb + (size_t)(f_base + ft * 16 + la) * 512 + k0 + lk * 8);
            acc[ft] = __builtin_amdgcn_mfma_f32_16x16x32_bf16(a, b, acc[ft], 0, 0, 0);
        }
    }

#pragma unroll
    for (int ft = 0; ft < 4; ++ft) {
#pragma unroll
        for (int r = 0; r < 4; ++r) {
            int n = m_base + lk * 4 + r;
            int d = ft * 16 + la;          // head-local feature
            ushort v = f2bf(acc[ft][r]);
            if (mat < 2) {
                ushort* base = ws + (mat == 0 ? QF_OFF : KF_OFF) + (size_t)fb * 262144;
                int blk = n >> 4, rr = n & 15;
                int half = d >> 5, lkk = (d >> 3) & 3, e = d & 7;
                base[(((size_t)blk * 2 + half) * 64 + lkk * 16 + rr) * 8 + e] = v;
            } else {
                ushort* base = ws + VF_OFF + (size_t)fb * 262144;
                int kb64 = n >> 6, kc = n & 63;
                int hf = kc >> 5, lkv = (kc >> 3) & 3, ev = kc & 7;
                int dt = d >> 4, lav = d & 15;
                base[((((size_t)kb64 * 4 + dt) * 2 + hf) * 64 + lkv * 16 + lav) * 8 + ev] = v;
            }
        }
    }
}

// ---------------- kernel 2: masked attention, 32 q-rows/wave, R9 schedule ----------------
// grid 2048: h = bid&7 (XCD-pinned), qb = (bid>>3)&31, ks = bid>>8 (0..7).
// 4 waves x 32 q-rows (128 q/block); 8 bodies of 64 keys (512 keys/block).
// Per body: [vmcnt(0) free-drain (everything in flight is 1 body old); barrier] ->
// pack adjv (32 ints) -> 1-VGPR bitmask, freeing adjv -> STAGE(next)+adjv(next)
// issued AT TOP (full-body ~1800cy cover > 900cy HBM) -> compute from LDS.
// Live VGPR ~116 < the (256,3) cap of ~170: no spills, 3 waves/SIMD.

#define STAGE(BUF, KB)                                                                     \
    {                                                                                      \
        const ushort* sbase_ = (wave < 2) ? Kh : Vh;                                       \
        ushort(*dbuf_)[512] = (wave < 2) ? kbuf[BUF] : vbuf[BUF];                          \
        int t0_ = (wave & 1) * 4;                                                          \
        _Pragma("unroll")                                                                  \
        for (int t_ = 0; t_ < 4; ++t_) {                                                   \
            int tile_ = t0_ + t_;                                                          \
            const ushort* src_ = sbase_ +                                                  \
                (((size_t)(KB) * 4 + (tile_ >> 1)) * 2 + (tile_ & 1)) * 512 + lane * 8;    \
            __builtin_amdgcn_global_load_lds(                                              \
                (const __attribute__((address_space(1))) unsigned int*)src_,               \
                (__attribute__((address_space(3))) unsigned int*)&dbuf_[tile_][0],         \
                16, 0, 0);                                                                 \
        }                                                                                  \
    }

#define ADJ_LOAD(KB)                                                                       \
    {                                                                                      \
        _Pragma("unroll")                                                                  \
        for (int qs_ = 0; qs_ < 2; ++qs_)                                                  \
            _Pragma("unroll")                                                              \
            for (int kt_ = 0; kt_ < 4; ++kt_)                                              \
                _Pragma("unroll")                                                          \
                for (int r_ = 0; r_ < 4; ++r_)                                             \
                    adjv[qs_ * 16 + kt_ * 4 + r_] = __builtin_nontemporal_load(            \
                        adjw + (size_t)(qs_ * 16 + lk * 4 + r_) * 4096 +                   \
                        (size_t)(KB) * 64 + kt_ * 16 + la);                                \
    }

__global__ __launch_bounds__(256, 3) void attn_kernel(const int* __restrict__ adj,
                                                      const ushort* __restrict__ ws,
                                                      ushort* __restrict__ pacc,
                                                      float* __restrict__ pden) {
    __shared__ ushort kbuf[2][8][512];   // 16KB
    __shared__ ushort vbuf[2][8][512];   // 16KB
    __shared__ ushort P[4][32][72];      // 18.4KB per-wave P staging

    int bid = blockIdx.x;
    int h = bid & 7, qb = (bid >> 3) & 31, ks = bid >> 8;
    int wave = threadIdx.x >> 6, lane = threadIdx.x & 63;
    int la = lane & 15, lk = lane >> 4;
    int q0w = qb * 128 + wave * 32;

    const ushort* Qh = ws + QF_OFF + (size_t)h * 262144;
    const ushort* Kh = ws + KF_OFF + (size_t)h * 262144;
    const ushort* Vh = ws + VF_OFF + (size_t)h * 262144;
    const int* adjw = adj + (size_t)h * 16777216 + (size_t)q0w * 4096;

    bf16x8 qa[2][2];
#pragma unroll
    for (int qs = 0; qs < 2; ++qs)
#pragma unroll
        for (int hf = 0; hf < 2; ++hf)
            qa[qs][hf] = *reinterpret_cast<const bf16x8*>(
                Qh + ((((size_t)((q0w >> 4) + qs)) * 2 + hf) * 64 + lane) * 8);

    f32x4 acc[2][4];
    float den[2][4];
#pragma unroll
    for (int qs = 0; qs < 2; ++qs)
#pragma unroll
        for (int r = 0; r < 4; ++r) {
            acc[qs][r] = (f32x4){0.f, 0.f, 0.f, 0.f};
            den[qs][r] = 0.f;
        }

    const f32x4 zero = {0.f, 0.f, 0.f, 0.f};
    int kbase = ks * 8;   // bodies kbase .. kbase+7 (64 keys each)

    // prologue — issue body 0's stage + adj (one ~900cy wait at body-0 top)
    int adjv[32];
    STAGE(0, kbase)
    __builtin_amdgcn_sched_barrier(0);
    ADJ_LOAD(kbase)
    __builtin_amdgcn_sched_barrier(0);

    for (int it = 0; it < 8; ++it) {
        int kb = kbase + it;
        int cur = it & 1;

        // body top: everything in flight was issued a full body ago -> free drain
        asm volatile("s_waitcnt vmcnt(0)" ::: "memory");
        __builtin_amdgcn_s_barrier();

        // pack adjv -> one bitmask VGPR (bit j = qs*16 + kt*4 + r), freeing adjv
        unsigned int mbits = 0u;
#pragma unroll
        for (int j = 0; j < 32; ++j)
            mbits |= (adjv[j] != 0 ? 1u : 0u) << j;
        __builtin_amdgcn_sched_barrier(0);

        // issue next body's stage + adj AT TOP: full-body latency cover
        if (it < 7) {
            STAGE(cur ^ 1, kb + 1)
            __builtin_amdgcn_sched_barrier(0);
            ADJ_LOAD(kb + 1)
        }
        __builtin_amdgcn_sched_barrier(0);

        // QK^T from LDS (kf shared across both q-subtiles) + fused mask/exp
#pragma unroll
        for (int kt = 0; kt < 4; ++kt) {
            bf16x8 kf0 = *reinterpret_cast<const bf16x8*>(&kbuf[cur][kt * 2 + 0][lane * 8]);
            bf16x8 kf1 = *reinterpret_cast<const bf16x8*>(&kbuf[cur][kt * 2 + 1][lane * 8]);
#pragma unroll
            for (int qs = 0; qs < 2; ++qs) {
                f32x4 s = __builtin_amdgcn_mfma_f32_16x16x32_bf16(qa[qs][0], kf0, zero, 0, 0, 0);
                s = __builtin_amdgcn_mfma_f32_16x16x32_bf16(qa[qs][1], kf1, s, 0, 0, 0);
#pragma unroll
                for (int r = 0; r < 4; ++r) {
                    float sv = ((mbits >> (qs * 16 + kt * 4 + r)) & 1u) ? s[r] : -1e30f;
                    float e = __expf(sv);
                    den[qs][r] += e;
                    P[wave][qs * 16 + lk * 4 + r][kt * 16 + la] = f2bf(e);
                }
            }
        }

        // PV from LDS-staged V (vb read once, used by both q-subtiles)
        bf16x8 pa0q0 = *reinterpret_cast<const bf16x8*>(&P[wave][la][lk * 8]);
        bf16x8 pa1q0 = *reinterpret_cast<const bf16x8*>(&P[wave][la][32 + lk * 8]);
        bf16x8 pa0q1 = *reinterpret_cast<const bf16x8*>(&P[wave][16 + la][lk * 8]);
        bf16x8 pa1q1 = *reinterpret_cast<const bf16x8*>(&P[wave][16 + la][32 + lk * 8]);
#pragma unroll
        for (int dt = 0; dt < 4; ++dt) {
            bf16x8 vb0 = *reinterpret_cast<const bf16x8*>(&vbuf[cur][dt * 2 + 0][lane * 8]);
            bf16x8 vb1 = *reinterpret_cast<const bf16x8*>(&vbuf[cur][dt * 2 + 1][lane * 8]);
            acc[0][dt] = __builtin_amdgcn_mfma_f32_16x16x32_bf16(pa0q0, vb0, acc[0][dt], 0, 0, 0);
            acc[0][dt] = __builtin_amdgcn_mfma_f32_16x16x32_bf16(pa1q0, vb1, acc[0][dt], 0, 0, 0);
            acc[1][dt] = __builtin_amdgcn_mfma_f32_16x16x32_bf16(pa0q1, vb0, acc[1][dt], 0, 0, 0);
            acc[1][dt] = __builtin_amdgcn_mfma_f32_16x16x32_bf16(pa1q1, vb1, acc[1][dt], 0, 0, 0);
        }
    }

    // reduce den over the 16-lane key dimension
#pragma unroll
    for (int qs = 0; qs < 2; ++qs)
#pragma unroll
        for (int r = 0; r < 4; ++r)
#pragma unroll
            for (int mm = 1; mm < 16; mm <<= 1)
                den[qs][r] += __shfl_xor(den[qs][r], mm, 64);

    // store bf16 partial acc + f32 partial den
    ushort* pa_out = pacc + ((size_t)ks * 8 + h) * 4096 * 64;
#pragma unroll
    for (int qs = 0; qs < 2; ++qs)
#pragma unroll
        for (int dt = 0; dt < 4; ++dt)
#pragma unroll
            for (int r = 0; r < 4; ++r) {
                int q = q0w + qs * 16 + lk * 4 + r;
                __builtin_nontemporal_store(f2bf(acc[qs][dt][r]), pa_out + (size_t)q * 64 + dt * 16 + la);
            }
    if (la == 0) {
        float* pd = pden + ((size_t)ks * 8 + h) * 4096;
#pragma unroll
        for (int qs = 0; qs < 2; ++qs)
#pragma unroll
            for (int r = 0; r < 4; ++r)
                pd[q0w + qs * 16 + lk * 4 + r] = den[qs][r];
    }
}

// ---------------- kernel 3: combine bf16 partials + epilogue ----------------
__global__ __launch_bounds__(256) void combine_kernel(const float* __restrict__ x,
                                                      const ushort* __restrict__ pacc,
                                                      const float* __restrict__ pden,
                                                      float* __restrict__ out) {
    int idx = blockIdx.x * 256 + threadIdx.x;   // 524288 total
    int n = idx >> 7, fq = idx & 127;
    int h = fq >> 4;
    int d4 = (fq & 15) * 4;

    float4 o = make_float4(0.f, 0.f, 0.f, 0.f);
    float den = 0.f;
#pragma unroll
    for (int ksp = 0; ksp < 8; ++ksp) {
        const ushort* pa = pacc + (((size_t)ksp * 8 + h) * 4096 + n) * 64 + d4;
        ushort4 p = *reinterpret_cast<const ushort4*>(pa);
        o.x += bf2f(p.x); o.y += bf2f(p.y); o.z += bf2f(p.z); o.w += bf2f(p.w);
        den += pden[((size_t)ksp * 8 + h) * 4096 + n];
    }
    float4 xv = *reinterpret_cast<const float4*>(x + (size_t)n * 512 + fq * 4);
    float inv = 1.f / den;
    float4 r;
    r.x = o.x * inv + xv.x;
    r.y = o.y * inv + xv.y;
    r.z = o.z * inv + xv.z;
    r.w = o.w * inv + xv.w;
    r.x = (r.x > 0.f) ? r.x : (__expf(r.x) - 1.f);
    r.y = (r.y > 0.f) ? r.y : (__expf(r.y) - 1.f);
    r.z = (r.z > 0.f) ? r.z : (__expf(r.z) - 1.f);
    r.w = (r.w > 0.f) ? r.w : (__expf(r.w) - 1.f);
    *reinterpret_cast<float4*>(out + (size_t)n * 512 + fq * 4) = r;
}

extern "C" void kernel_launch(void* const* d_in, const int* in_sizes, int n_in,
                              void* d_out, int out_size, void* d_ws, size_t ws_size,
                              hipStream_t stream) {
    const float* x  = (const float*)d_in[0];
    const float* wq = (const float*)d_in[1];
    const float* wk = (const float*)d_in[2];
    const float* wv = (const float*)d_in[3];
    const int*   adj = (const int*)d_in[4];
    float* out = (float*)d_out;
    ushort* ws = (ushort*)d_ws;
    ushort* pacc = ws + PACC_OFF;
    float* pden = (float*)(ws + PDEN_USHORT_OFF);

    cvt_kernel<<<2816, 256, 0, stream>>>(x, wq, wk, wv, ws);
    qkv_kernel<<<dim3(24, 64), 256, 0, stream>>>(ws);
    attn_kernel<<<2048, 256, 0, stream>>>(adj, ws, pacc, pden);
    combine_kernel<<<2048, 256, 0, stream>>>(x, pacc, pden, out);
}